// Round 5
// baseline (265.334 us; speedup 1.0000x reference)
//
#include <hip/hip_runtime.h>
#include <hip/hip_bf16.h>
#include <cstdint>
#include <cstddef>

#define DEVINL __device__ __forceinline__

typedef __attribute__((ext_vector_type(4))) float   f32x4;
typedef __bf16 bf16x8 __attribute__((ext_vector_type(8)));
typedef __attribute__((ext_vector_type(4))) short   short4v;
typedef __attribute__((ext_vector_type(4))) float   float4v;

static constexpr int DIM = 1024;
static constexpr int NTOK = 4096;

// ---------- scalar helpers ----------
DEVINL unsigned short f2bf(float f) {
  unsigned u = __float_as_uint(f);
  u += 0x7FFF + ((u >> 16) & 1);
  return (unsigned short)(u >> 16);
}
DEVINL float bf2f(unsigned short s) {
  return __uint_as_float(((unsigned)s) << 16);
}

DEVINL void gll16(const void* g, void* l) {
  __builtin_amdgcn_global_load_lds(
      (const __attribute__((address_space(1))) void*)g,
      (__attribute__((address_space(3))) void*)l, 16, 0, 0);
}

// =====================================================================
// 256x256xK 8-wave core — m201-style 8-phase schedule (4 phases/K-tile,
// 2 barriers/phase, ONE vmcnt(6) per K-tile at p3, 3-half-tiles-ahead
// prefetch). A,B K-major (NT GEMM). T2 swizzle (0 bank conflicts).
//
// LDS ring: 8 half-slots x 16 KB. even tile: A0=s1 B1=s2 A1=s3 B0=s4;
// odd tile: A0=s5 B1=s6 A1=s7 B0=s0.
// Stage rotation during tile T: p0->B0(T+1), p1->A0(T+2), p2->B1(T+2),
// p3->A1(T+2). Each stage hits the slot read in the PREVIOUS phase —
// safe because every phase ends with a barrier (all waves' reads of that
// slot drained at their lgkmcnt(0) before that barrier).
// vmcnt(6) at p3: newest 3 halves (A0/B1/A1 of T+2) may stay in flight;
// everything read during tile T+1 is guaranteed landed. vmcnt(0) at
// tile NT-2 covers the tail.
// Quadrants: p0=(m0,n0) reads A0+B0 (12 ds_read_b128); p1=(m0,n1) reads
// B1 (4); p2=(m1,n1) reads A1 (8); p3=(m1,n0) reads nothing (B0 held).
// =====================================================================
DEVINL void core256(const unsigned short* __restrict__ A, int lda,
                    const unsigned short* __restrict__ B, int ldb,
                    int K, int brow, int bcol, f32x4 acc[8][4])
{
  __shared__ unsigned short lds[65536];   // 128 KB = 8 slots x 8192 ushorts
  const int t = threadIdx.x;
  const int w = t >> 6, l = t & 63;
  const int wr = w >> 2, wc = w & 3;
  const int srow = l >> 3;
  const int scol = ((l & 7) ^ srow) << 3;                    // inverse-swizzled source col
  const int l15 = l & 15;
  const int cs0 = (((l >> 4) << 3)        ^ ((l & 7) << 3)); // swizzled read col, ks=0
  const int cs1 = ((32 + ((l >> 4) << 3)) ^ ((l & 7) << 3)); // ks=1

  const unsigned short* aL = A + (size_t)(brow * 256 + srow) * lda + scol;
  const unsigned short* bL = B + (size_t)(bcol * 256 + srow) * ldb + scol;

#pragma unroll
  for (int m = 0; m < 8; ++m)
#pragma unroll
    for (int n = 0; n < 4; ++n) {
      f32x4 z = {0.f, 0.f, 0.f, 0.f};
      acc[m][n] = z;
    }

  // ---- staging: one source-call = 8 KB (each wave 1 KB); 2 calls = half ----
#define STA(slot, h, r, kt)                                                    \
  gll16(aL + (size_t)((r)*128 + (h)*64 + (w << 3)) * lda + (size_t)(kt)*64,    \
        lds + (slot)*8192 + ((r)*64 + (w << 3)) * 64)
#define STB(slot, h, r, kt)                                                    \
  { const int g16_ = w + (r)*8;                                                \
    gll16(bL + (size_t)((g16_>>2)*64 + (h)*32 + (g16_&3)*8) * ldb              \
              + (size_t)(kt)*64,                                               \
          lds + (slot)*8192 + ((g16_>>2)*32 + (g16_&3)*8) * 64); }
  // ---- register-fragment loads from a half-slot ----
#define LDAm(dst, slot)                                                        \
  _Pragma("unroll")                                                            \
  for (int m4 = 0; m4 < 4; ++m4) {                                             \
    const unsigned short* p_ = lds + (slot)*8192 + (wr*64 + m4*16 + l15)*64;   \
    dst[m4][0] = *(const bf16x8*)(p_ + cs0);                                   \
    dst[m4][1] = *(const bf16x8*)(p_ + cs1);                                   \
  }
#define LDBm(dst, slot)                                                        \
  _Pragma("unroll")                                                            \
  for (int n2 = 0; n2 < 2; ++n2) {                                             \
    const unsigned short* p_ = lds + (slot)*8192 + (wc*32 + n2*16 + l15)*64;   \
    dst[n2][0] = *(const bf16x8*)(p_ + cs0);                                   \
    dst[n2][1] = *(const bf16x8*)(p_ + cs1);                                   \
  }
#define MF(mh, nh, br)                                                         \
  __builtin_amdgcn_s_setprio(1);                                               \
  _Pragma("unroll")                                                            \
  for (int m4 = 0; m4 < 4; ++m4)                                               \
  _Pragma("unroll")                                                            \
  for (int n2 = 0; n2 < 2; ++n2) {                                             \
    f32x4 c_ = acc[(mh)*4 + m4][(nh)*2 + n2];                                  \
    c_ = __builtin_amdgcn_mfma_f32_16x16x32_bf16(af[m4][0], br[n2][0], c_, 0,0,0); \
    c_ = __builtin_amdgcn_mfma_f32_16x16x32_bf16(af[m4][1], br[n2][1], c_, 0,0,0); \
    acc[(mh)*4 + m4][(nh)*2 + n2] = c_;                                        \
  }                                                                            \
  __builtin_amdgcn_s_setprio(0);
#define LGW()  do { asm volatile("s_waitcnt lgkmcnt(0)" ::: "memory");         \
                    __builtin_amdgcn_sched_barrier(0); } while (0)
#define BARR() do { asm volatile("" ::: "memory");                             \
                    __builtin_amdgcn_s_barrier();                              \
                    asm volatile("" ::: "memory"); } while (0)

  const int NT = K >> 6;

  // ---- prologue: A0(0)s1 B1(0)s2 A1(0)s3 B0(0)s4 A0(1)s5 B1(1)s6 A1(1)s7 ----
  STA(1, 0, 0, 0); STA(1, 0, 1, 0);
  STB(2, 1, 0, 0); STB(2, 1, 1, 0);
  STA(3, 1, 0, 0); STA(3, 1, 1, 0);
  STB(4, 0, 0, 0); STB(4, 0, 1, 0);
  STA(5, 0, 0, 1); STA(5, 0, 1, 1);
  STB(6, 1, 0, 1); STB(6, 1, 1, 1);
  STA(7, 1, 0, 1); STA(7, 1, 1, 1);
  asm volatile("s_waitcnt vmcnt(6)" ::: "memory");  // tile0 halves landed
  BARR();

  bf16x8 af[4][2], b0r[2][2], b1r[2][2];

#define TILE(kt, sA0, sB1, sA1, sB0, nB0, nA0, nB1, nA1)                       \
  {                                                                            \
    /* p0: (m0,n0) */                                                          \
    LDAm(af, sA0);                                                             \
    LDBm(b0r, sB0);                                                            \
    if ((kt) + 1 < NT) { STB(nB0, 0, 0, (kt)+1); STB(nB0, 0, 1, (kt)+1); }     \
    asm volatile("s_waitcnt lgkmcnt(8)" ::: "memory");                         \
    BARR(); LGW(); MF(0, 0, b0r); BARR();                                      \
    /* p1: (m0,n1) */                                                          \
    LDBm(b1r, sB1);                                                            \
    if ((kt) + 2 < NT) { STA(nA0, 0, 0, (kt)+2); STA(nA0, 0, 1, (kt)+2); }     \
    BARR(); LGW(); MF(0, 1, b1r); BARR();                                      \
    /* p2: (m1,n1) */                                                          \
    LDAm(af, sA1);                                                             \
    if ((kt) + 2 < NT) { STB(nB1, 1, 0, (kt)+2); STB(nB1, 1, 1, (kt)+2); }     \
    BARR(); LGW(); MF(1, 1, b1r); BARR();                                      \
    /* p3: (m1,n0) — no ds_reads; counted vmcnt */                             \
    if ((kt) + 2 < NT) { STA(nA1, 1, 0, (kt)+2); STA(nA1, 1, 1, (kt)+2); }     \
    if ((kt) + 2 >= NT) { asm volatile("s_waitcnt vmcnt(0)" ::: "memory"); }   \
    else                { asm volatile("s_waitcnt vmcnt(6)" ::: "memory"); }   \
    BARR(); MF(1, 0, b0r); BARR();                                             \
  }

  for (int kt = 0; kt < NT; kt += 2) {
    TILE(kt,     1, 2, 3, 4,  0, 1, 2, 3);   // even tile
    TILE(kt + 1, 5, 6, 7, 0,  4, 5, 6, 7);   // odd tile
  }
#undef TILE
#undef STA
#undef STB
#undef LDAm
#undef LDBm
#undef MF
#undef LGW
#undef BARR
}

// ---------- scores: S = bf16( (A B^T) * scale ), [4096 x 4096] ----------
__global__ __launch_bounds__(512, 2)
void gemm256_scores(const unsigned short* __restrict__ A,
                    const unsigned short* __restrict__ B,
                    unsigned short* __restrict__ S, float scale)
{
  f32x4 acc[8][4];
  core256(A, DIM, B, DIM, DIM, blockIdx.y, blockIdx.x, acc);

  const int t = threadIdx.x, w = t >> 6, l = t & 63;
  const int wr = w >> 2, wc = w & 3;
  const int r4 = (l >> 4) * 4, c = l & 15;
  const int row0 = blockIdx.y * 256 + wr * 128;
  const int col0 = blockIdx.x * 256 + wc * 64;
#pragma unroll
  for (int mf = 0; mf < 8; ++mf)
#pragma unroll
    for (int nf = 0; nf < 4; ++nf)
#pragma unroll
      for (int i = 0; i < 4; ++i)
        S[(size_t)(row0 + mf*16 + r4 + i) * NTOK + col0 + nf*16 + c] =
            f2bf(acc[mf][nf][i] * scale);
}

// ---------- merged QKV: grid.z = 6; v outputs transposed ----------
__global__ __launch_bounds__(512, 2)
void qkv256(const unsigned short* __restrict__ x1, const unsigned short* __restrict__ x2,
            const unsigned short* __restrict__ W6,
            const float* bq1, const float* bk1, const float* bv1,
            const float* bq2, const float* bk2, const float* bv2,
            unsigned short* q1, unsigned short* k1, unsigned short* v1T,
            unsigned short* q2, unsigned short* k2, unsigned short* v2T)
{
  const int g = blockIdx.z;
  const unsigned short* A = (g < 3) ? x1 : x2;
  const unsigned short* W = W6 + (size_t)g * (DIM * DIM);
  const float* bias = (g == 0) ? bq1 : (g == 1) ? bk1 : (g == 2) ? bv1
                    : (g == 3) ? bq2 : (g == 4) ? bk2 : bv2;
  unsigned short* out = (g == 0) ? q1 : (g == 1) ? k1 : (g == 2) ? v1T
                      : (g == 3) ? q2 : (g == 4) ? k2 : v2T;
  const bool vT = (g == 2 || g == 5);

  f32x4 acc[8][4];
  core256(A, DIM, W, DIM, DIM, blockIdx.y, blockIdx.x, acc);

  const int t = threadIdx.x, w = t >> 6, l = t & 63;
  const int wr = w >> 2, wc = w & 3;
  const int r4 = (l >> 4) * 4, c = l & 15;
  const int row0 = blockIdx.y * 256 + wr * 128;
  const int col0 = blockIdx.x * 256 + wc * 64;

  float bias_v[4];
#pragma unroll
  for (int nf = 0; nf < 4; ++nf) bias_v[nf] = bias[col0 + nf*16 + c];

  if (!vT) {
#pragma unroll
    for (int mf = 0; mf < 8; ++mf)
#pragma unroll
      for (int nf = 0; nf < 4; ++nf)
#pragma unroll
        for (int i = 0; i < 4; ++i)
          out[(size_t)(row0 + mf*16 + r4 + i) * DIM + col0 + nf*16 + c] =
              f2bf(acc[mf][nf][i] + bias_v[nf]);
  } else {
#pragma unroll
    for (int mf = 0; mf < 8; ++mf)
#pragma unroll
      for (int nf = 0; nf < 4; ++nf) {
        short4v pk;
#pragma unroll
        for (int i = 0; i < 4; ++i) pk[i] = (short)f2bf(acc[mf][nf][i] + bias_v[nf]);
        *(short4v*)(out + (size_t)(col0 + nf*16 + c) * NTOK + row0 + mf*16 + r4) = pk;
      }
  }
}

// ---------- fused PV: C[4096 x 2048] = [P1@V1 | P2@V2], split-K=2 ----------
__global__ __launch_bounds__(512, 2)
void pv_fused(const unsigned short* __restrict__ S1,
              const unsigned short* __restrict__ S2,
              const unsigned short* __restrict__ vTcat,
              float* __restrict__ out, float* __restrict__ P)
{
  const int bx = blockIdx.x, by = blockIdx.y, z = blockIdx.z;
  const unsigned short* A = ((bx < 4) ? S1 : S2) + (size_t)z * 2048;
  const unsigned short* B = vTcat + (size_t)z * 2048;

  f32x4 acc[8][4];
  core256(A, NTOK, B, NTOK, 2048, by, bx, acc);

  const int t = threadIdx.x, w = t >> 6, l = t & 63;
  const int wr = w >> 2, wc = w & 3;
  const int r4 = (l >> 4) * 4, c = l & 15;
  const int row0 = by * 256 + wr * 128;
  const int col0 = bx * 256 + wc * 64;

#pragma unroll
  for (int mf = 0; mf < 8; ++mf)
#pragma unroll
    for (int nf = 0; nf < 4; ++nf)
#pragma unroll
      for (int i = 0; i < 4; ++i) {
        const int r = row0 + mf*16 + r4 + i;
        const int cg = col0 + nf*16 + c;
        if (z) {
          P[(size_t)r * 2048 + cg] = acc[mf][nf][i];
        } else {
          float* dst = (cg < 1024) ? (out + (size_t)r * 1024 + cg)
                                   : (out + 4194304 + (size_t)r * 1024 + (cg - 1024));
          *dst = acc[mf][nf][i];
        }
      }
}

// out(+4M) += P, remapping [4096 x 2048] partial onto the two context halves
__global__ __launch_bounds__(256)
void add_pv(float* __restrict__ out, const float* __restrict__ P)
{
  const int idx = blockIdx.x * 256 + threadIdx.x;   // 2M threads, 4 floats each
  const int r  = idx >> 9;
  const int c4 = (idx & 511) << 2;
  const float4v p = *(const float4v*)(P + (size_t)r * 2048 + c4);
  float* dst = (c4 < 1024) ? (out + (size_t)r * 1024 + c4)
                           : (out + 4194304 + (size_t)r * 1024 + (c4 - 1024));
  float4v a = *(const float4v*)dst;
#pragma unroll
  for (int j = 0; j < 4; ++j) a[j] += p[j];
  *(float4v*)dst = a;
}

// ---------- row softmax, in place on bf16 [4096 x 4096] ----------
__global__ __launch_bounds__(256)
void softmax_inplace(unsigned short* __restrict__ S)
{
  const int row = blockIdx.x;
  unsigned short* r = S + (size_t)row * NTOK;
  const int t = threadIdx.x, wave = t >> 6, lane = t & 63;
  __shared__ float red[4];

  bf16x8 d0 = *(const bf16x8*)(r + t * 8);
  bf16x8 d1 = *(const bf16x8*)(r + 2048 + t * 8);
  float v[16];
  {
    const unsigned short* p0 = (const unsigned short*)&d0;
    const unsigned short* p1 = (const unsigned short*)&d1;
#pragma unroll
    for (int j = 0; j < 8; ++j) { v[j] = bf2f(p0[j]); v[8 + j] = bf2f(p1[j]); }
  }
  float mx = v[0];
#pragma unroll
  for (int j = 1; j < 16; ++j) mx = fmaxf(mx, v[j]);
#pragma unroll
  for (int o = 32; o > 0; o >>= 1) mx = fmaxf(mx, __shfl_xor(mx, o));
  if (lane == 0) red[wave] = mx;
  __syncthreads();
  mx = fmaxf(fmaxf(red[0], red[1]), fmaxf(red[2], red[3]));

  float s = 0.f;
#pragma unroll
  for (int j = 0; j < 16; ++j) { v[j] = __expf(v[j] - mx); s += v[j]; }
#pragma unroll
  for (int o = 32; o > 0; o >>= 1) s += __shfl_xor(s, o);
  __syncthreads();
  if (lane == 0) red[wave] = s;
  __syncthreads();
  s = red[0] + red[1] + red[2] + red[3];
  const float inv = 1.0f / s;

  unsigned short o0[8], o1[8];
#pragma unroll
  for (int j = 0; j < 8; ++j) { o0[j] = f2bf(v[j] * inv); o1[j] = f2bf(v[8 + j] * inv); }
  *(bf16x8*)(r + t * 8)        = *(const bf16x8*)o0;
  *(bf16x8*)(r + 2048 + t * 8) = *(const bf16x8*)o1;
}

// ---------- fp32 -> bf16 converters ----------
__global__ __launch_bounds__(256)
void cvt2(const float* __restrict__ a, const float* __restrict__ b,
          unsigned short* __restrict__ oa, unsigned short* __restrict__ ob)
{
  const float* in = blockIdx.y ? b : a;
  unsigned short* out = blockIdx.y ? ob : oa;
  const size_t i = ((size_t)blockIdx.x * 256 + threadIdx.x) * 4;
  float4v x = *(const float4v*)(in + i);
  short4v o;
#pragma unroll
  for (int j = 0; j < 4; ++j) o[j] = (short)f2bf(x[j]);
  *(short4v*)(out + i) = o;
}

__global__ __launch_bounds__(256)
void cvt_w(const float* w0, const float* w1, const float* w2,
           const float* w3, const float* w4, const float* w5,
           unsigned short* __restrict__ W6)
{
  const float* srcs[6] = {w0, w1, w2, w3, w4, w5};
  const float* in = srcs[blockIdx.y];
  unsigned short* out = W6 + (size_t)blockIdx.y * (DIM * DIM);
  const size_t i = ((size_t)blockIdx.x * 256 + threadIdx.x) * 4;
  float4v x = *(const float4v*)(in + i);
  short4v o;
#pragma unroll
  for (int j = 0; j < 4; ++j) o[j] = (short)f2bf(x[j]);
  *(short4v*)(out + i) = o;
}

// ---------- host launcher ----------
extern "C" void kernel_launch(void* const* d_in, const int* in_sizes, int n_in,
                              void* d_out, int out_size, void* d_ws, size_t ws_size,
                              hipStream_t stream)
{
  const float* x1  = (const float*)d_in[0];
  const float* x2  = (const float*)d_in[1];
  const float* Wq1 = (const float*)d_in[2];  const float* bq1 = (const float*)d_in[3];
  const float* Wk1 = (const float*)d_in[4];  const float* bk1 = (const float*)d_in[5];
  const float* Wv1 = (const float*)d_in[6];  const float* bv1 = (const float*)d_in[7];
  const float* Wq2 = (const float*)d_in[8];  const float* bq2 = (const float*)d_in[9];
  const float* Wk2 = (const float*)d_in[10]; const float* bk2 = (const float*)d_in[11];
  const float* Wv2 = (const float*)d_in[12]; const float* bv2 = (const float*)d_in[13];
  float* out = (float*)d_out;

  // ws layout (ushort units):
  //  [0,16M):    x1b(4M) x2b(4M) W6(6M) pad -> later S1 [4096x4096]
  //  [16M,32M):  S2
  //  [32M,48M):  q1 k1 q2 k2 (4M each)      -> later P (fp32 partial, 32 MB)
  //  [48M,56M):  v1T v2T (vTcat, [2048 x 4096])
  unsigned short* ws  = (unsigned short*)d_ws;
  const size_t NTD = (size_t)NTOK * DIM;           // 4M elems
  const size_t SM  = (size_t)NTOK * NTOK;          // 16M elems
  unsigned short* x1b = ws;
  unsigned short* x2b = x1b + NTD;
  unsigned short* W6  = x2b + NTD;
  unsigned short* S1  = ws;
  unsigned short* S2  = ws + SM;
  unsigned short* q1  = ws + 2 * SM;
  unsigned short* k1  = q1 + NTD;
  unsigned short* q2  = k1 + NTD;
  unsigned short* k2  = q2 + NTD;
  unsigned short* vT  = k2 + NTD;                  // v1T followed by v2T
  unsigned short* v1T = vT;
  unsigned short* v2T = vT + NTD;
  float* P = (float*)q1;                           // 32 MB partial over dead q/k

  const dim3 blk(256);
  cvt2 <<<dim3(NTD / 1024, 2), blk, 0, stream>>>(x1, x2, x1b, x2b);
  cvt_w<<<dim3((DIM * DIM) / 1024, 6), blk, 0, stream>>>(Wq1, Wk1, Wv1, Wq2, Wk2, Wv2, W6);

  qkv256<<<dim3(DIM / 256, NTOK / 256, 6), dim3(512), 0, stream>>>(
      x1b, x2b, W6, bq1, bk1, bv1, bq2, bk2, bv2, q1, k1, v1T, q2, k2, v2T);

  const float scale = 0.03125f;  // 1/sqrt(1024)

  // scores + softmax (S1 overwrites dead x/W region)
  gemm256_scores<<<dim3(NTOK / 256, NTOK / 256), dim3(512), 0, stream>>>(q2, k1, S1, scale);
  softmax_inplace<<<dim3(NTOK), blk, 0, stream>>>(S1);
  gemm256_scores<<<dim3(NTOK / 256, NTOK / 256), dim3(512), 0, stream>>>(q1, k2, S2, scale);
  softmax_inplace<<<dim3(NTOK), blk, 0, stream>>>(S2);

  // fused PV over [v1T; v2T], split-K=2 (q/k region now dead -> P)
  pv_fused<<<dim3(8, NTOK / 256, 2), dim3(512), 0, stream>>>(S1, S2, vT, out, P);
  add_pv<<<dim3(8192), blk, 0, stream>>>(out, P);
}

// Round 6
// 264.672 us; speedup vs baseline: 1.0025x; 1.0025x over previous
//
#include <hip/hip_runtime.h>
#include <hip/hip_bf16.h>
#include <cstdint>
#include <cstddef>

#define DEVINL __device__ __forceinline__

typedef __attribute__((ext_vector_type(4))) float   f32x4;
typedef __bf16 bf16x8 __attribute__((ext_vector_type(8)));
typedef __attribute__((ext_vector_type(4))) short   short4v;
typedef __attribute__((ext_vector_type(4))) float   float4v;

static constexpr int DIM = 1024;
static constexpr int NTOK = 4096;

// ---------- scalar helpers ----------
DEVINL unsigned short f2bf(float f) {
  unsigned u = __float_as_uint(f);
  u += 0x7FFF + ((u >> 16) & 1);
  return (unsigned short)(u >> 16);
}
DEVINL float bf2f(unsigned short s) {
  return __uint_as_float(((unsigned)s) << 16);
}

DEVINL void gll16(const void* g, void* l) {
  __builtin_amdgcn_global_load_lds(
      (const __attribute__((address_space(1))) void*)g,
      (__attribute__((address_space(3))) void*)l, 16, 0, 0);
}

// =====================================================================
// 256x256xK 8-wave core — 8-phase schedule, COMPILER-SCHEDULED LDS waits.
// vs round 5: all manual lgkmcnt waits and sched_barrier(0) fences
// REMOVED (m141: order-pinning defeats the compiler's fine-grained
// lgkmcnt scheduling). Barriers keep "memory" clobbers: that is what
// makes the stage-overwrite ledger sound (reads of a slot are used, and
// therefore drained by compiler-emitted waits, before the phase-ending
// barrier; stages into that slot happen only after it).
//
// LDS ring: 8 half-slots x 16 KB. even tile: A0=s1 B1=s2 A1=s3 B0=s4;
// odd tile: A0=s5 B1=s6 A1=s7 B0=s0.
// Stage rotation during tile T: p0->B0(T+1), p1->A0(T+2), p2->B1(T+2),
// p3->A1(T+2). ONE counted vmcnt(6) per K-tile at p3 (3 newest halves
// may stay in flight; everything tile T+1 reads has landed). vmcnt(0)
// only for the last two tiles.
// =====================================================================
DEVINL void core256(const unsigned short* __restrict__ A, int lda,
                    const unsigned short* __restrict__ B, int ldb,
                    int K, int brow, int bcol, f32x4 acc[8][4])
{
  __shared__ unsigned short lds[65536];   // 128 KB = 8 slots x 8192 ushorts
  const int t = threadIdx.x;
  const int w = t >> 6, l = t & 63;
  const int wr = w >> 2, wc = w & 3;
  const int srow = l >> 3;
  const int scol = ((l & 7) ^ srow) << 3;                    // inverse-swizzled source col
  const int l15 = l & 15;
  const int cs0 = (((l >> 4) << 3)        ^ ((l & 7) << 3)); // swizzled read col, ks=0
  const int cs1 = ((32 + ((l >> 4) << 3)) ^ ((l & 7) << 3)); // ks=1

  const unsigned short* aL = A + (size_t)(brow * 256 + srow) * lda + scol;
  const unsigned short* bL = B + (size_t)(bcol * 256 + srow) * ldb + scol;

#pragma unroll
  for (int m = 0; m < 8; ++m)
#pragma unroll
    for (int n = 0; n < 4; ++n) {
      f32x4 z = {0.f, 0.f, 0.f, 0.f};
      acc[m][n] = z;
    }

  // ---- staging: one source-call = 8 KB (each wave 1 KB); 2 calls = half ----
#define STA(slot, h, r, kt)                                                    \
  gll16(aL + (size_t)((r)*128 + (h)*64 + (w << 3)) * lda + (size_t)(kt)*64,    \
        lds + (slot)*8192 + ((r)*64 + (w << 3)) * 64)
#define STB(slot, h, r, kt)                                                    \
  { const int g16_ = w + (r)*8;                                                \
    gll16(bL + (size_t)((g16_>>2)*64 + (h)*32 + (g16_&3)*8) * ldb              \
              + (size_t)(kt)*64,                                               \
          lds + (slot)*8192 + ((g16_>>2)*32 + (g16_&3)*8) * 64); }
  // ---- register-fragment loads from a half-slot (compiler-scheduled) ----
#define LDAm(dst, slot)                                                        \
  _Pragma("unroll")                                                            \
  for (int m4 = 0; m4 < 4; ++m4) {                                             \
    const unsigned short* p_ = lds + (slot)*8192 + (wr*64 + m4*16 + l15)*64;   \
    dst[m4][0] = *(const bf16x8*)(p_ + cs0);                                   \
    dst[m4][1] = *(const bf16x8*)(p_ + cs1);                                   \
  }
#define LDBm(dst, slot)                                                        \
  _Pragma("unroll")                                                            \
  for (int n2 = 0; n2 < 2; ++n2) {                                             \
    const unsigned short* p_ = lds + (slot)*8192 + (wc*32 + n2*16 + l15)*64;   \
    dst[n2][0] = *(const bf16x8*)(p_ + cs0);                                   \
    dst[n2][1] = *(const bf16x8*)(p_ + cs1);                                   \
  }
#define MF(mh, nh, br)                                                         \
  __builtin_amdgcn_s_setprio(1);                                               \
  _Pragma("unroll")                                                            \
  for (int m4 = 0; m4 < 4; ++m4)                                               \
  _Pragma("unroll")                                                            \
  for (int n2 = 0; n2 < 2; ++n2) {                                             \
    f32x4 c_ = acc[(mh)*4 + m4][(nh)*2 + n2];                                  \
    c_ = __builtin_amdgcn_mfma_f32_16x16x32_bf16(af[m4][0], br[n2][0], c_, 0,0,0); \
    c_ = __builtin_amdgcn_mfma_f32_16x16x32_bf16(af[m4][1], br[n2][1], c_, 0,0,0); \
    acc[(mh)*4 + m4][(nh)*2 + n2] = c_;                                        \
  }                                                                            \
  __builtin_amdgcn_s_setprio(0);
#define BARR() do { asm volatile("" ::: "memory");                             \
                    __builtin_amdgcn_s_barrier();                              \
                    asm volatile("" ::: "memory"); } while (0)

  const int NT = K >> 6;

  // ---- prologue: A0(0)s1 B1(0)s2 A1(0)s3 B0(0)s4 A0(1)s5 B1(1)s6 A1(1)s7 ----
  STA(1, 0, 0, 0); STA(1, 0, 1, 0);
  STB(2, 1, 0, 0); STB(2, 1, 1, 0);
  STA(3, 1, 0, 0); STA(3, 1, 1, 0);
  STB(4, 0, 0, 0); STB(4, 0, 1, 0);
  STA(5, 0, 0, 1); STA(5, 0, 1, 1);
  STB(6, 1, 0, 1); STB(6, 1, 1, 1);
  STA(7, 1, 0, 1); STA(7, 1, 1, 1);
  asm volatile("s_waitcnt vmcnt(6)" ::: "memory");  // tile0 halves landed
  BARR();

  bf16x8 af[4][2], b0r[2][2], b1r[2][2];

#define TILE(kt, sA0, sB1, sA1, sB0, nB0, nA0, nB1, nA1)                       \
  {                                                                            \
    /* p0: (m0,n0) */                                                          \
    LDAm(af, sA0);                                                             \
    LDBm(b0r, sB0);                                                            \
    if ((kt) + 1 < NT) { STB(nB0, 0, 0, (kt)+1); STB(nB0, 0, 1, (kt)+1); }     \
    BARR(); MF(0, 0, b0r); BARR();                                             \
    /* p1: (m0,n1) */                                                          \
    LDBm(b1r, sB1);                                                            \
    if ((kt) + 2 < NT) { STA(nA0, 0, 0, (kt)+2); STA(nA0, 0, 1, (kt)+2); }     \
    BARR(); MF(0, 1, b1r); BARR();                                             \
    /* p2: (m1,n1) */                                                          \
    LDAm(af, sA1);                                                             \
    if ((kt) + 2 < NT) { STB(nB1, 1, 0, (kt)+2); STB(nB1, 1, 1, (kt)+2); }     \
    BARR(); MF(1, 1, b1r); BARR();                                             \
    /* p3: (m1,n0) — no ds_reads; counted vmcnt */                             \
    if ((kt) + 2 < NT) { STA(nA1, 1, 0, (kt)+2); STA(nA1, 1, 1, (kt)+2); }     \
    if ((kt) + 2 >= NT) { asm volatile("s_waitcnt vmcnt(0)" ::: "memory"); }   \
    else                { asm volatile("s_waitcnt vmcnt(6)" ::: "memory"); }   \
    BARR(); MF(1, 0, b0r); BARR();                                             \
  }

  for (int kt = 0; kt < NT; kt += 2) {
    TILE(kt,     1, 2, 3, 4,  0, 1, 2, 3);   // even tile
    TILE(kt + 1, 5, 6, 7, 0,  4, 5, 6, 7);   // odd tile
  }
#undef TILE
#undef STA
#undef STB
#undef LDAm
#undef LDBm
#undef MF
#undef BARR
}

// ---------- scores: S = bf16( (A B^T) * scale ), [4096 x 4096] ----------
__global__ __launch_bounds__(512, 2)
void gemm256_scores(const unsigned short* __restrict__ A,
                    const unsigned short* __restrict__ B,
                    unsigned short* __restrict__ S, float scale)
{
  f32x4 acc[8][4];
  core256(A, DIM, B, DIM, DIM, blockIdx.y, blockIdx.x, acc);

  const int t = threadIdx.x, w = t >> 6, l = t & 63;
  const int wr = w >> 2, wc = w & 3;
  const int r4 = (l >> 4) * 4, c = l & 15;
  const int row0 = blockIdx.y * 256 + wr * 128;
  const int col0 = blockIdx.x * 256 + wc * 64;
#pragma unroll
  for (int mf = 0; mf < 8; ++mf)
#pragma unroll
    for (int nf = 0; nf < 4; ++nf)
#pragma unroll
      for (int i = 0; i < 4; ++i)
        S[(size_t)(row0 + mf*16 + r4 + i) * NTOK + col0 + nf*16 + c] =
            f2bf(acc[mf][nf][i] * scale);
}

// ---------- merged QKV: grid.z = 6; v outputs transposed ----------
__global__ __launch_bounds__(512, 2)
void qkv256(const unsigned short* __restrict__ x1, const unsigned short* __restrict__ x2,
            const unsigned short* __restrict__ W6,
            const float* bq1, const float* bk1, const float* bv1,
            const float* bq2, const float* bk2, const float* bv2,
            unsigned short* q1, unsigned short* k1, unsigned short* v1T,
            unsigned short* q2, unsigned short* k2, unsigned short* v2T)
{
  const int g = blockIdx.z;
  const unsigned short* A = (g < 3) ? x1 : x2;
  const unsigned short* W = W6 + (size_t)g * (DIM * DIM);
  const float* bias = (g == 0) ? bq1 : (g == 1) ? bk1 : (g == 2) ? bv1
                    : (g == 3) ? bq2 : (g == 4) ? bk2 : bv2;
  unsigned short* out = (g == 0) ? q1 : (g == 1) ? k1 : (g == 2) ? v1T
                      : (g == 3) ? q2 : (g == 4) ? k2 : v2T;
  const bool vT = (g == 2 || g == 5);

  f32x4 acc[8][4];
  core256(A, DIM, W, DIM, DIM, blockIdx.y, blockIdx.x, acc);

  const int t = threadIdx.x, w = t >> 6, l = t & 63;
  const int wr = w >> 2, wc = w & 3;
  const int r4 = (l >> 4) * 4, c = l & 15;
  const int row0 = blockIdx.y * 256 + wr * 128;
  const int col0 = blockIdx.x * 256 + wc * 64;

  float bias_v[4];
#pragma unroll
  for (int nf = 0; nf < 4; ++nf) bias_v[nf] = bias[col0 + nf*16 + c];

  if (!vT) {
#pragma unroll
    for (int mf = 0; mf < 8; ++mf)
#pragma unroll
      for (int nf = 0; nf < 4; ++nf)
#pragma unroll
        for (int i = 0; i < 4; ++i)
          out[(size_t)(row0 + mf*16 + r4 + i) * DIM + col0 + nf*16 + c] =
              f2bf(acc[mf][nf][i] + bias_v[nf]);
  } else {
#pragma unroll
    for (int mf = 0; mf < 8; ++mf)
#pragma unroll
      for (int nf = 0; nf < 4; ++nf) {
        short4v pk;
#pragma unroll
        for (int i = 0; i < 4; ++i) pk[i] = (short)f2bf(acc[mf][nf][i] + bias_v[nf]);
        *(short4v*)(out + (size_t)(col0 + nf*16 + c) * NTOK + row0 + mf*16 + r4) = pk;
      }
  }
}

// ---------- fused PV: C[4096 x 2048] = [P1@V1 | P2@V2], split-K=2 ----------
__global__ __launch_bounds__(512, 2)
void pv_fused(const unsigned short* __restrict__ S1,
              const unsigned short* __restrict__ S2,
              const unsigned short* __restrict__ vTcat,
              float* __restrict__ out, float* __restrict__ P)
{
  const int bx = blockIdx.x, by = blockIdx.y, z = blockIdx.z;
  const unsigned short* A = ((bx < 4) ? S1 : S2) + (size_t)z * 2048;
  const unsigned short* B = vTcat + (size_t)z * 2048;

  f32x4 acc[8][4];
  core256(A, NTOK, B, NTOK, 2048, by, bx, acc);

  const int t = threadIdx.x, w = t >> 6, l = t & 63;
  const int wr = w >> 2, wc = w & 3;
  const int r4 = (l >> 4) * 4, c = l & 15;
  const int row0 = by * 256 + wr * 128;
  const int col0 = bx * 256 + wc * 64;

#pragma unroll
  for (int mf = 0; mf < 8; ++mf)
#pragma unroll
    for (int nf = 0; nf < 4; ++nf)
#pragma unroll
      for (int i = 0; i < 4; ++i) {
        const int r = row0 + mf*16 + r4 + i;
        const int cg = col0 + nf*16 + c;
        if (z) {
          P[(size_t)r * 2048 + cg] = acc[mf][nf][i];
        } else {
          float* dst = (cg < 1024) ? (out + (size_t)r * 1024 + cg)
                                   : (out + 4194304 + (size_t)r * 1024 + (cg - 1024));
          *dst = acc[mf][nf][i];
        }
      }
}

// out(+4M) += P, remapping [4096 x 2048] partial onto the two context halves
__global__ __launch_bounds__(256)
void add_pv(float* __restrict__ out, const float* __restrict__ P)
{
  const int idx = blockIdx.x * 256 + threadIdx.x;   // 2M threads, 4 floats each
  const int r  = idx >> 9;
  const int c4 = (idx & 511) << 2;
  const float4v p = *(const float4v*)(P + (size_t)r * 2048 + c4);
  float* dst = (c4 < 1024) ? (out + (size_t)r * 1024 + c4)
                           : (out + 4194304 + (size_t)r * 1024 + (c4 - 1024));
  float4v a = *(const float4v*)dst;
#pragma unroll
  for (int j = 0; j < 4; ++j) a[j] += p[j];
  *(float4v*)dst = a;
}

// ---------- row softmax, in place on bf16 [4096 x 4096] ----------
__global__ __launch_bounds__(256)
void softmax_inplace(unsigned short* __restrict__ S)
{
  const int row = blockIdx.x;
  unsigned short* r = S + (size_t)row * NTOK;
  const int t = threadIdx.x, wave = t >> 6, lane = t & 63;
  __shared__ float red[4];

  bf16x8 d0 = *(const bf16x8*)(r + t * 8);
  bf16x8 d1 = *(const bf16x8*)(r + 2048 + t * 8);
  float v[16];
  {
    const unsigned short* p0 = (const unsigned short*)&d0;
    const unsigned short* p1 = (const unsigned short*)&d1;
#pragma unroll
    for (int j = 0; j < 8; ++j) { v[j] = bf2f(p0[j]); v[8 + j] = bf2f(p1[j]); }
  }
  float mx = v[0];
#pragma unroll
  for (int j = 1; j < 16; ++j) mx = fmaxf(mx, v[j]);
#pragma unroll
  for (int o = 32; o > 0; o >>= 1) mx = fmaxf(mx, __shfl_xor(mx, o));
  if (lane == 0) red[wave] = mx;
  __syncthreads();
  mx = fmaxf(fmaxf(red[0], red[1]), fmaxf(red[2], red[3]));

  float s = 0.f;
#pragma unroll
  for (int j = 0; j < 16; ++j) { v[j] = __expf(v[j] - mx); s += v[j]; }
#pragma unroll
  for (int o = 32; o > 0; o >>= 1) s += __shfl_xor(s, o);
  __syncthreads();
  if (lane == 0) red[wave] = s;
  __syncthreads();
  s = red[0] + red[1] + red[2] + red[3];
  const float inv = 1.0f / s;

  unsigned short o0[8], o1[8];
#pragma unroll
  for (int j = 0; j < 8; ++j) { o0[j] = f2bf(v[j] * inv); o1[j] = f2bf(v[8 + j] * inv); }
  *(bf16x8*)(r + t * 8)        = *(const bf16x8*)o0;
  *(bf16x8*)(r + 2048 + t * 8) = *(const bf16x8*)o1;
}

// ---------- fp32 -> bf16 converters ----------
__global__ __launch_bounds__(256)
void cvt2(const float* __restrict__ a, const float* __restrict__ b,
          unsigned short* __restrict__ oa, unsigned short* __restrict__ ob)
{
  const float* in = blockIdx.y ? b : a;
  unsigned short* out = blockIdx.y ? ob : oa;
  const size_t i = ((size_t)blockIdx.x * 256 + threadIdx.x) * 4;
  float4v x = *(const float4v*)(in + i);
  short4v o;
#pragma unroll
  for (int j = 0; j < 4; ++j) o[j] = (short)f2bf(x[j]);
  *(short4v*)(out + i) = o;
}

__global__ __launch_bounds__(256)
void cvt_w(const float* w0, const float* w1, const float* w2,
           const float* w3, const float* w4, const float* w5,
           unsigned short* __restrict__ W6)
{
  const float* srcs[6] = {w0, w1, w2, w3, w4, w5};
  const float* in = srcs[blockIdx.y];
  unsigned short* out = W6 + (size_t)blockIdx.y * (DIM * DIM);
  const size_t i = ((size_t)blockIdx.x * 256 + threadIdx.x) * 4;
  float4v x = *(const float4v*)(in + i);
  short4v o;
#pragma unroll
  for (int j = 0; j < 4; ++j) o[j] = (short)f2bf(x[j]);
  *(short4v*)(out + i) = o;
}

// ---------- host launcher ----------
extern "C" void kernel_launch(void* const* d_in, const int* in_sizes, int n_in,
                              void* d_out, int out_size, void* d_ws, size_t ws_size,
                              hipStream_t stream)
{
  const float* x1  = (const float*)d_in[0];
  const float* x2  = (const float*)d_in[1];
  const float* Wq1 = (const float*)d_in[2];  const float* bq1 = (const float*)d_in[3];
  const float* Wk1 = (const float*)d_in[4];  const float* bk1 = (const float*)d_in[5];
  const float* Wv1 = (const float*)d_in[6];  const float* bv1 = (const float*)d_in[7];
  const float* Wq2 = (const float*)d_in[8];  const float* bq2 = (const float*)d_in[9];
  const float* Wk2 = (const float*)d_in[10]; const float* bk2 = (const float*)d_in[11];
  const float* Wv2 = (const float*)d_in[12]; const float* bv2 = (const float*)d_in[13];
  float* out = (float*)d_out;

  // ws layout (ushort units):
  //  [0,16M):    x1b(4M) x2b(4M) W6(6M) pad -> later S1 [4096x4096]
  //  [16M,32M):  S2
  //  [32M,48M):  q1 k1 q2 k2 (4M each)      -> later P (fp32 partial, 32 MB)
  //  [48M,56M):  v1T v2T (vTcat, [2048 x 4096])
  unsigned short* ws  = (unsigned short*)d_ws;
  const size_t NTD = (size_t)NTOK * DIM;           // 4M elems
  const size_t SM  = (size_t)NTOK * NTOK;          // 16M elems
  unsigned short* x1b = ws;
  unsigned short* x2b = x1b + NTD;
  unsigned short* W6  = x2b + NTD;
  unsigned short* S1  = ws;
  unsigned short* S2  = ws + SM;
  unsigned short* q1  = ws + 2 * SM;
  unsigned short* k1  = q1 + NTD;
  unsigned short* q2  = k1 + NTD;
  unsigned short* k2  = q2 + NTD;
  unsigned short* vT  = k2 + NTD;                  // v1T followed by v2T
  unsigned short* v1T = vT;
  unsigned short* v2T = vT + NTD;
  float* P = (float*)q1;                           // 32 MB partial over dead q/k

  const dim3 blk(256);
  cvt2 <<<dim3(NTD / 1024, 2), blk, 0, stream>>>(x1, x2, x1b, x2b);
  cvt_w<<<dim3((DIM * DIM) / 1024, 6), blk, 0, stream>>>(Wq1, Wk1, Wv1, Wq2, Wk2, Wv2, W6);

  qkv256<<<dim3(DIM / 256, NTOK / 256, 6), dim3(512), 0, stream>>>(
      x1b, x2b, W6, bq1, bk1, bv1, bq2, bk2, bv2, q1, k1, v1T, q2, k2, v2T);

  const float scale = 0.03125f;  // 1/sqrt(1024)

  // scores + softmax (S1 overwrites dead x/W region)
  gemm256_scores<<<dim3(NTOK / 256, NTOK / 256), dim3(512), 0, stream>>>(q2, k1, S1, scale);
  softmax_inplace<<<dim3(NTOK), blk, 0, stream>>>(S1);
  gemm256_scores<<<dim3(NTOK / 256, NTOK / 256), dim3(512), 0, stream>>>(q1, k2, S2, scale);
  softmax_inplace<<<dim3(NTOK), blk, 0, stream>>>(S2);

  // fused PV over [v1T; v2T], split-K=2 (q/k region now dead -> P)
  pv_fused<<<dim3(8, NTOK / 256, 2), dim3(512), 0, stream>>>(S1, S2, vT, out, P);
  add_pv<<<dim3(8192), blk, 0, stream>>>(out, P);
}

// Round 7
// 262.773 us; speedup vs baseline: 1.0097x; 1.0072x over previous
//
#include <hip/hip_runtime.h>
#include <hip/hip_bf16.h>
#include <cstdint>
#include <cstddef>

#define DEVINL __device__ __forceinline__

typedef __attribute__((ext_vector_type(4))) float   f32x4;
typedef __bf16 bf16x8 __attribute__((ext_vector_type(8)));
typedef __attribute__((ext_vector_type(4))) short   short4v;
typedef __attribute__((ext_vector_type(4))) float   float4v;

static constexpr int DIM = 1024;
static constexpr int NTOK = 4096;

// ---------- scalar helpers ----------
DEVINL unsigned short f2bf(float f) {
  unsigned u = __float_as_uint(f);
  u += 0x7FFF + ((u >> 16) & 1);
  return (unsigned short)(u >> 16);
}
DEVINL float bf2f(unsigned short s) {
  return __uint_as_float(((unsigned)s) << 16);
}

DEVINL void gll16(const void* g, void* l) {
  __builtin_amdgcn_global_load_lds(
      (const __attribute__((address_space(1))) void*)g,
      (__attribute__((address_space(3))) void*)l, 16, 0, 0);
}

// =====================================================================
// 256x256xK 8-wave core — 8-phase schedule, compiler-scheduled LDS waits.
// KEY (round 7): __launch_bounds__(512, 1). acc[8][4] f32x4 alone = 128
// VGPRs; (512,2) forced a 128-VGPR budget -> accumulator spills +
// serialized ds_reads in every MFMA cluster. LDS (128 KB) already caps
// occupancy at 1 block/CU, so the 2-block register promise bought nothing.
//
// LDS ring: 8 half-slots x 16 KB. even tile: A0=s1 B1=s2 A1=s3 B0=s4;
// odd tile: A0=s5 B1=s6 A1=s7 B0=s0.
// Stage rotation during tile T: p0->B0(T+1), p1->A0(T+2), p2->B1(T+2),
// p3->A1(T+2). ONE counted vmcnt(6) per K-tile at p3. vmcnt(0) only for
// the last two tiles. T2 swizzle (0 bank conflicts, verified r3-r6).
// =====================================================================
DEVINL void core256(const unsigned short* __restrict__ A, int lda,
                    const unsigned short* __restrict__ B, int ldb,
                    int K, int brow, int bcol, f32x4 acc[8][4])
{
  __shared__ unsigned short lds[65536];   // 128 KB = 8 slots x 8192 ushorts
  const int t = threadIdx.x;
  const int w = t >> 6, l = t & 63;
  const int wr = w >> 2, wc = w & 3;
  const int srow = l >> 3;
  const int scol = ((l & 7) ^ srow) << 3;                    // inverse-swizzled source col
  const int l15 = l & 15;
  const int cs0 = (((l >> 4) << 3)        ^ ((l & 7) << 3)); // swizzled read col, ks=0
  const int cs1 = ((32 + ((l >> 4) << 3)) ^ ((l & 7) << 3)); // ks=1

  const unsigned short* aL = A + (size_t)(brow * 256 + srow) * lda + scol;
  const unsigned short* bL = B + (size_t)(bcol * 256 + srow) * ldb + scol;

#pragma unroll
  for (int m = 0; m < 8; ++m)
#pragma unroll
    for (int n = 0; n < 4; ++n) {
      f32x4 z = {0.f, 0.f, 0.f, 0.f};
      acc[m][n] = z;
    }

  // ---- staging: one source-call = 8 KB (each wave 1 KB); 2 calls = half ----
#define STA(slot, h, r, kt)                                                    \
  gll16(aL + (size_t)((r)*128 + (h)*64 + (w << 3)) * lda + (size_t)(kt)*64,    \
        lds + (slot)*8192 + ((r)*64 + (w << 3)) * 64)
#define STB(slot, h, r, kt)                                                    \
  { const int g16_ = w + (r)*8;                                                \
    gll16(bL + (size_t)((g16_>>2)*64 + (h)*32 + (g16_&3)*8) * ldb              \
              + (size_t)(kt)*64,                                               \
          lds + (slot)*8192 + ((g16_>>2)*32 + (g16_&3)*8) * 64); }
  // ---- register-fragment loads from a half-slot (compiler-scheduled) ----
#define LDAm(dst, slot)                                                        \
  _Pragma("unroll")                                                            \
  for (int m4 = 0; m4 < 4; ++m4) {                                             \
    const unsigned short* p_ = lds + (slot)*8192 + (wr*64 + m4*16 + l15)*64;   \
    dst[m4][0] = *(const bf16x8*)(p_ + cs0);                                   \
    dst[m4][1] = *(const bf16x8*)(p_ + cs1);                                   \
  }
#define LDBm(dst, slot)                                                        \
  _Pragma("unroll")                                                            \
  for (int n2 = 0; n2 < 2; ++n2) {                                             \
    const unsigned short* p_ = lds + (slot)*8192 + (wc*32 + n2*16 + l15)*64;   \
    dst[n2][0] = *(const bf16x8*)(p_ + cs0);                                   \
    dst[n2][1] = *(const bf16x8*)(p_ + cs1);                                   \
  }
#define MF(mh, nh, br)                                                         \
  __builtin_amdgcn_s_setprio(1);                                               \
  _Pragma("unroll")                                                            \
  for (int m4 = 0; m4 < 4; ++m4)                                               \
  _Pragma("unroll")                                                            \
  for (int n2 = 0; n2 < 2; ++n2) {                                             \
    f32x4 c_ = acc[(mh)*4 + m4][(nh)*2 + n2];                                  \
    c_ = __builtin_amdgcn_mfma_f32_16x16x32_bf16(af[m4][0], br[n2][0], c_, 0,0,0); \
    c_ = __builtin_amdgcn_mfma_f32_16x16x32_bf16(af[m4][1], br[n2][1], c_, 0,0,0); \
    acc[(mh)*4 + m4][(nh)*2 + n2] = c_;                                        \
  }                                                                            \
  __builtin_amdgcn_s_setprio(0);
#define BARR() do { asm volatile("" ::: "memory");                             \
                    __builtin_amdgcn_s_barrier();                              \
                    asm volatile("" ::: "memory"); } while (0)

  const int NT = K >> 6;

  // ---- prologue: A0(0)s1 B1(0)s2 A1(0)s3 B0(0)s4 A0(1)s5 B1(1)s6 A1(1)s7 ----
  STA(1, 0, 0, 0); STA(1, 0, 1, 0);
  STB(2, 1, 0, 0); STB(2, 1, 1, 0);
  STA(3, 1, 0, 0); STA(3, 1, 1, 0);
  STB(4, 0, 0, 0); STB(4, 0, 1, 0);
  STA(5, 0, 0, 1); STA(5, 0, 1, 1);
  STB(6, 1, 0, 1); STB(6, 1, 1, 1);
  STA(7, 1, 0, 1); STA(7, 1, 1, 1);
  asm volatile("s_waitcnt vmcnt(6)" ::: "memory");  // tile0 halves landed
  BARR();

  bf16x8 af[4][2], b0r[2][2], b1r[2][2];

#define TILE(kt, sA0, sB1, sA1, sB0, nB0, nA0, nB1, nA1)                       \
  {                                                                            \
    /* p0: (m0,n0) */                                                          \
    LDAm(af, sA0);                                                             \
    LDBm(b0r, sB0);                                                            \
    if ((kt) + 1 < NT) { STB(nB0, 0, 0, (kt)+1); STB(nB0, 0, 1, (kt)+1); }     \
    BARR(); MF(0, 0, b0r); BARR();                                             \
    /* p1: (m0,n1) */                                                          \
    LDBm(b1r, sB1);                                                            \
    if ((kt) + 2 < NT) { STA(nA0, 0, 0, (kt)+2); STA(nA0, 0, 1, (kt)+2); }     \
    BARR(); MF(0, 1, b1r); BARR();                                             \
    /* p2: (m1,n1) */                                                          \
    LDAm(af, sA1);                                                             \
    if ((kt) + 2 < NT) { STB(nB1, 1, 0, (kt)+2); STB(nB1, 1, 1, (kt)+2); }     \
    BARR(); MF(1, 1, b1r); BARR();                                             \
    /* p3: (m1,n0) — no ds_reads; counted vmcnt */                             \
    if ((kt) + 2 < NT) { STA(nA1, 1, 0, (kt)+2); STA(nA1, 1, 1, (kt)+2); }     \
    if ((kt) + 2 >= NT) { asm volatile("s_waitcnt vmcnt(0)" ::: "memory"); }   \
    else                { asm volatile("s_waitcnt vmcnt(6)" ::: "memory"); }   \
    BARR(); MF(1, 0, b0r); BARR();                                             \
  }

  for (int kt = 0; kt < NT; kt += 2) {
    TILE(kt,     1, 2, 3, 4,  0, 1, 2, 3);   // even tile
    TILE(kt + 1, 5, 6, 7, 0,  4, 5, 6, 7);   // odd tile
  }
#undef TILE
#undef STA
#undef STB
#undef LDAm
#undef LDBm
#undef MF
#undef BARR
}

// ---------- scores: S = bf16( (A B^T) * scale ), [4096 x 4096] ----------
__global__ __launch_bounds__(512, 1)
void gemm256_scores(const unsigned short* __restrict__ A,
                    const unsigned short* __restrict__ B,
                    unsigned short* __restrict__ S, float scale)
{
  f32x4 acc[8][4];
  core256(A, DIM, B, DIM, DIM, blockIdx.y, blockIdx.x, acc);

  const int t = threadIdx.x, w = t >> 6, l = t & 63;
  const int wr = w >> 2, wc = w & 3;
  const int r4 = (l >> 4) * 4, c = l & 15;
  const int row0 = blockIdx.y * 256 + wr * 128;
  const int col0 = blockIdx.x * 256 + wc * 64;
#pragma unroll
  for (int mf = 0; mf < 8; ++mf)
#pragma unroll
    for (int nf = 0; nf < 4; ++nf)
#pragma unroll
      for (int i = 0; i < 4; ++i)
        S[(size_t)(row0 + mf*16 + r4 + i) * NTOK + col0 + nf*16 + c] =
            f2bf(acc[mf][nf][i] * scale);
}

// ---------- merged QKV: grid.z = 6; v outputs transposed ----------
__global__ __launch_bounds__(512, 1)
void qkv256(const unsigned short* __restrict__ x1, const unsigned short* __restrict__ x2,
            const unsigned short* __restrict__ W6,
            const float* bq1, const float* bk1, const float* bv1,
            const float* bq2, const float* bk2, const float* bv2,
            unsigned short* q1, unsigned short* k1, unsigned short* v1T,
            unsigned short* q2, unsigned short* k2, unsigned short* v2T)
{
  const int g = blockIdx.z;
  const unsigned short* A = (g < 3) ? x1 : x2;
  const unsigned short* W = W6 + (size_t)g * (DIM * DIM);
  const float* bias = (g == 0) ? bq1 : (g == 1) ? bk1 : (g == 2) ? bv1
                    : (g == 3) ? bq2 : (g == 4) ? bk2 : bv2;
  unsigned short* out = (g == 0) ? q1 : (g == 1) ? k1 : (g == 2) ? v1T
                      : (g == 3) ? q2 : (g == 4) ? k2 : v2T;
  const bool vT = (g == 2 || g == 5);

  f32x4 acc[8][4];
  core256(A, DIM, W, DIM, DIM, blockIdx.y, blockIdx.x, acc);

  const int t = threadIdx.x, w = t >> 6, l = t & 63;
  const int wr = w >> 2, wc = w & 3;
  const int r4 = (l >> 4) * 4, c = l & 15;
  const int row0 = blockIdx.y * 256 + wr * 128;
  const int col0 = blockIdx.x * 256 + wc * 64;

  float bias_v[4];
#pragma unroll
  for (int nf = 0; nf < 4; ++nf) bias_v[nf] = bias[col0 + nf*16 + c];

  if (!vT) {
#pragma unroll
    for (int mf = 0; mf < 8; ++mf)
#pragma unroll
      for (int nf = 0; nf < 4; ++nf)
#pragma unroll
        for (int i = 0; i < 4; ++i)
          out[(size_t)(row0 + mf*16 + r4 + i) * DIM + col0 + nf*16 + c] =
              f2bf(acc[mf][nf][i] + bias_v[nf]);
  } else {
#pragma unroll
    for (int mf = 0; mf < 8; ++mf)
#pragma unroll
      for (int nf = 0; nf < 4; ++nf) {
        short4v pk;
#pragma unroll
        for (int i = 0; i < 4; ++i) pk[i] = (short)f2bf(acc[mf][nf][i] + bias_v[nf]);
        *(short4v*)(out + (size_t)(col0 + nf*16 + c) * NTOK + row0 + mf*16 + r4) = pk;
      }
  }
}

// ---------- fused PV: C[4096 x 2048] = [P1@V1 | P2@V2], split-K=2 ----------
__global__ __launch_bounds__(512, 1)
void pv_fused(const unsigned short* __restrict__ S1,
              const unsigned short* __restrict__ S2,
              const unsigned short* __restrict__ vTcat,
              float* __restrict__ out, float* __restrict__ P)
{
  const int bx = blockIdx.x, by = blockIdx.y, z = blockIdx.z;
  const unsigned short* A = ((bx < 4) ? S1 : S2) + (size_t)z * 2048;
  const unsigned short* B = vTcat + (size_t)z * 2048;

  f32x4 acc[8][4];
  core256(A, NTOK, B, NTOK, 2048, by, bx, acc);

  const int t = threadIdx.x, w = t >> 6, l = t & 63;
  const int wr = w >> 2, wc = w & 3;
  const int r4 = (l >> 4) * 4, c = l & 15;
  const int row0 = by * 256 + wr * 128;
  const int col0 = bx * 256 + wc * 64;

#pragma unroll
  for (int mf = 0; mf < 8; ++mf)
#pragma unroll
    for (int nf = 0; nf < 4; ++nf)
#pragma unroll
      for (int i = 0; i < 4; ++i) {
        const int r = row0 + mf*16 + r4 + i;
        const int cg = col0 + nf*16 + c;
        if (z) {
          P[(size_t)r * 2048 + cg] = acc[mf][nf][i];
        } else {
          float* dst = (cg < 1024) ? (out + (size_t)r * 1024 + cg)
                                   : (out + 4194304 + (size_t)r * 1024 + (cg - 1024));
          *dst = acc[mf][nf][i];
        }
      }
}

// out(+4M) += P, remapping [4096 x 2048] partial onto the two context halves
__global__ __launch_bounds__(256)
void add_pv(float* __restrict__ out, const float* __restrict__ P)
{
  const int idx = blockIdx.x * 256 + threadIdx.x;   // 2M threads, 4 floats each
  const int r  = idx >> 9;
  const int c4 = (idx & 511) << 2;
  const float4v p = *(const float4v*)(P + (size_t)r * 2048 + c4);
  float* dst = (c4 < 1024) ? (out + (size_t)r * 1024 + c4)
                           : (out + 4194304 + (size_t)r * 1024 + (c4 - 1024));
  float4v a = *(const float4v*)dst;
#pragma unroll
  for (int j = 0; j < 4; ++j) a[j] += p[j];
  *(float4v*)dst = a;
}

// ---------- row softmax, in place on bf16 [4096 x 4096] ----------
__global__ __launch_bounds__(256)
void softmax_inplace(unsigned short* __restrict__ S)
{
  const int row = blockIdx.x;
  unsigned short* r = S + (size_t)row * NTOK;
  const int t = threadIdx.x, wave = t >> 6, lane = t & 63;
  __shared__ float red[4];

  bf16x8 d0 = *(const bf16x8*)(r + t * 8);
  bf16x8 d1 = *(const bf16x8*)(r + 2048 + t * 8);
  float v[16];
  {
    const unsigned short* p0 = (const unsigned short*)&d0;
    const unsigned short* p1 = (const unsigned short*)&d1;
#pragma unroll
    for (int j = 0; j < 8; ++j) { v[j] = bf2f(p0[j]); v[8 + j] = bf2f(p1[j]); }
  }
  float mx = v[0];
#pragma unroll
  for (int j = 1; j < 16; ++j) mx = fmaxf(mx, v[j]);
#pragma unroll
  for (int o = 32; o > 0; o >>= 1) mx = fmaxf(mx, __shfl_xor(mx, o));
  if (lane == 0) red[wave] = mx;
  __syncthreads();
  mx = fmaxf(fmaxf(red[0], red[1]), fmaxf(red[2], red[3]));

  float s = 0.f;
#pragma unroll
  for (int j = 0; j < 16; ++j) { v[j] = __expf(v[j] - mx); s += v[j]; }
#pragma unroll
  for (int o = 32; o > 0; o >>= 1) s += __shfl_xor(s, o);
  __syncthreads();
  if (lane == 0) red[wave] = s;
  __syncthreads();
  s = red[0] + red[1] + red[2] + red[3];
  const float inv = 1.0f / s;

  unsigned short o0[8], o1[8];
#pragma unroll
  for (int j = 0; j < 8; ++j) { o0[j] = f2bf(v[j] * inv); o1[j] = f2bf(v[8 + j] * inv); }
  *(bf16x8*)(r + t * 8)        = *(const bf16x8*)o0;
  *(bf16x8*)(r + 2048 + t * 8) = *(const bf16x8*)o1;
}

// ---------- fp32 -> bf16 converters ----------
__global__ __launch_bounds__(256)
void cvt2(const float* __restrict__ a, const float* __restrict__ b,
          unsigned short* __restrict__ oa, unsigned short* __restrict__ ob)
{
  const float* in = blockIdx.y ? b : a;
  unsigned short* out = blockIdx.y ? ob : oa;
  const size_t i = ((size_t)blockIdx.x * 256 + threadIdx.x) * 4;
  float4v x = *(const float4v*)(in + i);
  short4v o;
#pragma unroll
  for (int j = 0; j < 4; ++j) o[j] = (short)f2bf(x[j]);
  *(short4v*)(out + i) = o;
}

__global__ __launch_bounds__(256)
void cvt_w(const float* w0, const float* w1, const float* w2,
           const float* w3, const float* w4, const float* w5,
           unsigned short* __restrict__ W6)
{
  const float* srcs[6] = {w0, w1, w2, w3, w4, w5};
  const float* in = srcs[blockIdx.y];
  unsigned short* out = W6 + (size_t)blockIdx.y * (DIM * DIM);
  const size_t i = ((size_t)blockIdx.x * 256 + threadIdx.x) * 4;
  float4v x = *(const float4v*)(in + i);
  short4v o;
#pragma unroll
  for (int j = 0; j < 4; ++j) o[j] = (short)f2bf(x[j]);
  *(short4v*)(out + i) = o;
}

// ---------- host launcher ----------
extern "C" void kernel_launch(void* const* d_in, const int* in_sizes, int n_in,
                              void* d_out, int out_size, void* d_ws, size_t ws_size,
                              hipStream_t stream)
{
  const float* x1  = (const float*)d_in[0];
  const float* x2  = (const float*)d_in[1];
  const float* Wq1 = (const float*)d_in[2];  const float* bq1 = (const float*)d_in[3];
  const float* Wk1 = (const float*)d_in[4];  const float* bk1 = (const float*)d_in[5];
  const float* Wv1 = (const float*)d_in[6];  const float* bv1 = (const float*)d_in[7];
  const float* Wq2 = (const float*)d_in[8];  const float* bq2 = (const float*)d_in[9];
  const float* Wk2 = (const float*)d_in[10]; const float* bk2 = (const float*)d_in[11];
  const float* Wv2 = (const float*)d_in[12]; const float* bv2 = (const float*)d_in[13];
  float* out = (float*)d_out;

  // ws layout (ushort units):
  //  [0,16M):    x1b(4M) x2b(4M) W6(6M) pad -> later S1 [4096x4096]
  //  [16M,32M):  S2
  //  [32M,48M):  q1 k1 q2 k2 (4M each)      -> later P (fp32 partial, 32 MB)
  //  [48M,56M):  v1T v2T (vTcat, [2048 x 4096])
  unsigned short* ws  = (unsigned short*)d_ws;
  const size_t NTD = (size_t)NTOK * DIM;           // 4M elems
  const size_t SM  = (size_t)NTOK * NTOK;          // 16M elems
  unsigned short* x1b = ws;
  unsigned short* x2b = x1b + NTD;
  unsigned short* W6  = x2b + NTD;
  unsigned short* S1  = ws;
  unsigned short* S2  = ws + SM;
  unsigned short* q1  = ws + 2 * SM;
  unsigned short* k1  = q1 + NTD;
  unsigned short* q2  = k1 + NTD;
  unsigned short* k2  = q2 + NTD;
  unsigned short* vT  = k2 + NTD;                  // v1T followed by v2T
  unsigned short* v1T = vT;
  unsigned short* v2T = vT + NTD;
  float* P = (float*)q1;                           // 32 MB partial over dead q/k

  const dim3 blk(256);
  cvt2 <<<dim3(NTD / 1024, 2), blk, 0, stream>>>(x1, x2, x1b, x2b);
  cvt_w<<<dim3((DIM * DIM) / 1024, 6), blk, 0, stream>>>(Wq1, Wk1, Wv1, Wq2, Wk2, Wv2, W6);

  qkv256<<<dim3(DIM / 256, NTOK / 256, 6), dim3(512), 0, stream>>>(
      x1b, x2b, W6, bq1, bk1, bv1, bq2, bk2, bv2, q1, k1, v1T, q2, k2, v2T);

  const float scale = 0.03125f;  // 1/sqrt(1024)

  // scores + softmax (S1 overwrites dead x/W region)
  gemm256_scores<<<dim3(NTOK / 256, NTOK / 256), dim3(512), 0, stream>>>(q2, k1, S1, scale);
  softmax_inplace<<<dim3(NTOK), blk, 0, stream>>>(S1);
  gemm256_scores<<<dim3(NTOK / 256, NTOK / 256), dim3(512), 0, stream>>>(q1, k2, S2, scale);
  softmax_inplace<<<dim3(NTOK), blk, 0, stream>>>(S2);

  // fused PV over [v1T; v2T], split-K=2 (q/k region now dead -> P)
  pv_fused<<<dim3(8, NTOK / 256, 2), dim3(512), 0, stream>>>(S1, S2, vT, out, P);
  add_pv<<<dim3(8192), blk, 0, stream>>>(out, P);
}

// Round 8
// 259.124 us; speedup vs baseline: 1.0240x; 1.0141x over previous
//
#include <hip/hip_runtime.h>
#include <hip/hip_bf16.h>
#include <cstdint>
#include <cstddef>

#define DEVINL __device__ __forceinline__

typedef __attribute__((ext_vector_type(4))) float   f32x4;
typedef __bf16 bf16x8 __attribute__((ext_vector_type(8)));
typedef __attribute__((ext_vector_type(4))) short   short4v;
typedef __attribute__((ext_vector_type(4))) float   float4v;

static constexpr int DIM = 1024;
static constexpr int NTOK = 4096;

// ---------- scalar helpers ----------
DEVINL unsigned short f2bf(float f) {
  unsigned u = __float_as_uint(f);
  u += 0x7FFF + ((u >> 16) & 1);
  return (unsigned short)(u >> 16);
}
DEVINL float bf2f(unsigned short s) {
  return __uint_as_float(((unsigned)s) << 16);
}

DEVINL void gll16(const void* g, void* l) {
  __builtin_amdgcn_global_load_lds(
      (const __attribute__((address_space(1))) void*)g,
      (__attribute__((address_space(3))) void*)l, 16, 0, 0);
}

// ---------- T1: bijective XCD chunk swizzle ----------
// HW assigns flat blockIdx round-robin to the 8 XCDs. Remap so each XCD
// owns a CONTIGUOUS chunk of virtual bids, decoded bx-fastest: co-resident
// blocks on one XCD then share A-panels (same by) and B-panels (same bx),
// shrinking the per-XCD per-K-step staging working set to ~0.5 MB << 4 MB L2.
// Requires nwg % 8 == 0 (true: 256, 384, 256) for bijectivity (m204).
struct B3 { int bx, by, bz; };
DEVINL B3 xcd_remap(int GX, int GY, int GZ) {
  const int flat = blockIdx.x + GX * (blockIdx.y + GY * blockIdx.z);
  const int nwg  = GX * GY * GZ;
  const int chunk = nwg >> 3;
  const int vbid = (flat & 7) * chunk + (flat >> 3);
  B3 r;
  r.bx = vbid % GX;
  r.by = (vbid / GX) % GY;
  r.bz = vbid / (GX * GY);
  return r;
}

// =====================================================================
// 256x256xK 8-wave core — 8-phase schedule, compiler-scheduled LDS waits.
// LDS ring: 8 half-slots x 16 KB. even tile: A0=s1 B1=s2 A1=s3 B0=s4;
// odd tile: A0=s5 B1=s6 A1=s7 B0=s0.
// Stage rotation during tile T: p0->B0(T+1), p1->A0(T+2), p2->B1(T+2),
// p3->A1(T+2). ONE counted vmcnt(6) per K-tile at p3. vmcnt(0) only for
// the last two tiles. T2 swizzle (0 bank conflicts, verified r3-r7).
// =====================================================================
DEVINL void core256(const unsigned short* __restrict__ A, int lda,
                    const unsigned short* __restrict__ B, int ldb,
                    int K, int brow, int bcol, f32x4 acc[8][4])
{
  __shared__ unsigned short lds[65536];   // 128 KB = 8 slots x 8192 ushorts
  const int t = threadIdx.x;
  const int w = t >> 6, l = t & 63;
  const int wr = w >> 2, wc = w & 3;
  const int srow = l >> 3;
  const int scol = ((l & 7) ^ srow) << 3;                    // inverse-swizzled source col
  const int l15 = l & 15;
  const int cs0 = (((l >> 4) << 3)        ^ ((l & 7) << 3)); // swizzled read col, ks=0
  const int cs1 = ((32 + ((l >> 4) << 3)) ^ ((l & 7) << 3)); // ks=1

  const unsigned short* aL = A + (size_t)(brow * 256 + srow) * lda + scol;
  const unsigned short* bL = B + (size_t)(bcol * 256 + srow) * ldb + scol;

#pragma unroll
  for (int m = 0; m < 8; ++m)
#pragma unroll
    for (int n = 0; n < 4; ++n) {
      f32x4 z = {0.f, 0.f, 0.f, 0.f};
      acc[m][n] = z;
    }

  // ---- staging: one source-call = 8 KB (each wave 1 KB); 2 calls = half ----
#define STA(slot, h, r, kt)                                                    \
  gll16(aL + (size_t)((r)*128 + (h)*64 + (w << 3)) * lda + (size_t)(kt)*64,    \
        lds + (slot)*8192 + ((r)*64 + (w << 3)) * 64)
#define STB(slot, h, r, kt)                                                    \
  { const int g16_ = w + (r)*8;                                                \
    gll16(bL + (size_t)((g16_>>2)*64 + (h)*32 + (g16_&3)*8) * ldb              \
              + (size_t)(kt)*64,                                               \
          lds + (slot)*8192 + ((g16_>>2)*32 + (g16_&3)*8) * 64); }
  // ---- register-fragment loads from a half-slot (compiler-scheduled) ----
#define LDAm(dst, slot)                                                        \
  _Pragma("unroll")                                                            \
  for (int m4 = 0; m4 < 4; ++m4) {                                             \
    const unsigned short* p_ = lds + (slot)*8192 + (wr*64 + m4*16 + l15)*64;   \
    dst[m4][0] = *(const bf16x8*)(p_ + cs0);                                   \
    dst[m4][1] = *(const bf16x8*)(p_ + cs1);                                   \
  }
#define LDBm(dst, slot)                                                        \
  _Pragma("unroll")                                                            \
  for (int n2 = 0; n2 < 2; ++n2) {                                             \
    const unsigned short* p_ = lds + (slot)*8192 + (wc*32 + n2*16 + l15)*64;   \
    dst[n2][0] = *(const bf16x8*)(p_ + cs0);                                   \
    dst[n2][1] = *(const bf16x8*)(p_ + cs1);                                   \
  }
#define MF(mh, nh, br)                                                         \
  __builtin_amdgcn_s_setprio(1);                                               \
  _Pragma("unroll")                                                            \
  for (int m4 = 0; m4 < 4; ++m4)                                               \
  _Pragma("unroll")                                                            \
  for (int n2 = 0; n2 < 2; ++n2) {                                             \
    f32x4 c_ = acc[(mh)*4 + m4][(nh)*2 + n2];                                  \
    c_ = __builtin_amdgcn_mfma_f32_16x16x32_bf16(af[m4][0], br[n2][0], c_, 0,0,0); \
    c_ = __builtin_amdgcn_mfma_f32_16x16x32_bf16(af[m4][1], br[n2][1], c_, 0,0,0); \
    acc[(mh)*4 + m4][(nh)*2 + n2] = c_;                                        \
  }                                                                            \
  __builtin_amdgcn_s_setprio(0);
#define BARR() do { asm volatile("" ::: "memory");                             \
                    __builtin_amdgcn_s_barrier();                              \
                    asm volatile("" ::: "memory"); } while (0)

  const int NT = K >> 6;

  // ---- prologue: A0(0)s1 B1(0)s2 A1(0)s3 B0(0)s4 A0(1)s5 B1(1)s6 A1(1)s7 ----
  STA(1, 0, 0, 0); STA(1, 0, 1, 0);
  STB(2, 1, 0, 0); STB(2, 1, 1, 0);
  STA(3, 1, 0, 0); STA(3, 1, 1, 0);
  STB(4, 0, 0, 0); STB(4, 0, 1, 0);
  STA(5, 0, 0, 1); STA(5, 0, 1, 1);
  STB(6, 1, 0, 1); STB(6, 1, 1, 1);
  STA(7, 1, 0, 1); STA(7, 1, 1, 1);
  asm volatile("s_waitcnt vmcnt(6)" ::: "memory");  // tile0 halves landed
  BARR();

  bf16x8 af[4][2], b0r[2][2], b1r[2][2];

#define TILE(kt, sA0, sB1, sA1, sB0, nB0, nA0, nB1, nA1)                       \
  {                                                                            \
    /* p0: (m0,n0) */                                                          \
    LDAm(af, sA0);                                                             \
    LDBm(b0r, sB0);                                                            \
    if ((kt) + 1 < NT) { STB(nB0, 0, 0, (kt)+1); STB(nB0, 0, 1, (kt)+1); }     \
    BARR(); MF(0, 0, b0r); BARR();                                             \
    /* p1: (m0,n1) */                                                          \
    LDBm(b1r, sB1);                                                            \
    if ((kt) + 2 < NT) { STA(nA0, 0, 0, (kt)+2); STA(nA0, 0, 1, (kt)+2); }     \
    BARR(); MF(0, 1, b1r); BARR();                                             \
    /* p2: (m1,n1) */                                                          \
    LDAm(af, sA1);                                                             \
    if ((kt) + 2 < NT) { STB(nB1, 1, 0, (kt)+2); STB(nB1, 1, 1, (kt)+2); }     \
    BARR(); MF(1, 1, b1r); BARR();                                             \
    /* p3: (m1,n0) — no ds_reads; counted vmcnt */                             \
    if ((kt) + 2 < NT) { STA(nA1, 1, 0, (kt)+2); STA(nA1, 1, 1, (kt)+2); }     \
    if ((kt) + 2 >= NT) { asm volatile("s_waitcnt vmcnt(0)" ::: "memory"); }   \
    else                { asm volatile("s_waitcnt vmcnt(6)" ::: "memory"); }   \
    BARR(); MF(1, 0, b0r); BARR();                                             \
  }

  for (int kt = 0; kt < NT; kt += 2) {
    TILE(kt,     1, 2, 3, 4,  0, 1, 2, 3);   // even tile
    TILE(kt + 1, 5, 6, 7, 0,  4, 5, 6, 7);   // odd tile
  }
#undef TILE
#undef STA
#undef STB
#undef LDAm
#undef LDBm
#undef MF
#undef BARR
}

// ---------- scores: S = bf16( (A B^T) * scale ), [4096 x 4096] ----------
__global__ __launch_bounds__(512, 1)
void gemm256_scores(const unsigned short* __restrict__ A,
                    const unsigned short* __restrict__ B,
                    unsigned short* __restrict__ S, float scale)
{
  const B3 b = xcd_remap(16, 16, 1);
  f32x4 acc[8][4];
  core256(A, DIM, B, DIM, DIM, b.by, b.bx, acc);

  const int t = threadIdx.x, w = t >> 6, l = t & 63;
  const int wr = w >> 2, wc = w & 3;
  const int r4 = (l >> 4) * 4, c = l & 15;
  const int row0 = b.by * 256 + wr * 128;
  const int col0 = b.bx * 256 + wc * 64;
#pragma unroll
  for (int mf = 0; mf < 8; ++mf)
#pragma unroll
    for (int nf = 0; nf < 4; ++nf)
#pragma unroll
      for (int i = 0; i < 4; ++i)
        S[(size_t)(row0 + mf*16 + r4 + i) * NTOK + col0 + nf*16 + c] =
            f2bf(acc[mf][nf][i] * scale);
}

// ---------- merged QKV: grid.z = 6; v outputs transposed ----------
__global__ __launch_bounds__(512, 1)
void qkv256(const unsigned short* __restrict__ x1, const unsigned short* __restrict__ x2,
            const unsigned short* __restrict__ W6,
            const float* bq1, const float* bk1, const float* bv1,
            const float* bq2, const float* bk2, const float* bv2,
            unsigned short* q1, unsigned short* k1, unsigned short* v1T,
            unsigned short* q2, unsigned short* k2, unsigned short* v2T)
{
  const B3 b = xcd_remap(4, 16, 6);
  const int g = b.bz;
  const unsigned short* A = (g < 3) ? x1 : x2;
  const unsigned short* W = W6 + (size_t)g * (DIM * DIM);
  const float* bias = (g == 0) ? bq1 : (g == 1) ? bk1 : (g == 2) ? bv1
                    : (g == 3) ? bq2 : (g == 4) ? bk2 : bv2;
  unsigned short* out = (g == 0) ? q1 : (g == 1) ? k1 : (g == 2) ? v1T
                      : (g == 3) ? q2 : (g == 4) ? k2 : v2T;
  const bool vT = (g == 2 || g == 5);

  f32x4 acc[8][4];
  core256(A, DIM, W, DIM, DIM, b.by, b.bx, acc);

  const int t = threadIdx.x, w = t >> 6, l = t & 63;
  const int wr = w >> 2, wc = w & 3;
  const int r4 = (l >> 4) * 4, c = l & 15;
  const int row0 = b.by * 256 + wr * 128;
  const int col0 = b.bx * 256 + wc * 64;

  float bias_v[4];
#pragma unroll
  for (int nf = 0; nf < 4; ++nf) bias_v[nf] = bias[col0 + nf*16 + c];

  if (!vT) {
#pragma unroll
    for (int mf = 0; mf < 8; ++mf)
#pragma unroll
      for (int nf = 0; nf < 4; ++nf)
#pragma unroll
        for (int i = 0; i < 4; ++i)
          out[(size_t)(row0 + mf*16 + r4 + i) * DIM + col0 + nf*16 + c] =
              f2bf(acc[mf][nf][i] + bias_v[nf]);
  } else {
#pragma unroll
    for (int mf = 0; mf < 8; ++mf)
#pragma unroll
      for (int nf = 0; nf < 4; ++nf) {
        short4v pk;
#pragma unroll
        for (int i = 0; i < 4; ++i) pk[i] = (short)f2bf(acc[mf][nf][i] + bias_v[nf]);
        *(short4v*)(out + (size_t)(col0 + nf*16 + c) * NTOK + row0 + mf*16 + r4) = pk;
      }
  }
}

// ---------- fused PV: C[4096 x 2048] = [P1@V1 | P2@V2], split-K=2 ----------
__global__ __launch_bounds__(512, 1)
void pv_fused(const unsigned short* __restrict__ S1,
              const unsigned short* __restrict__ S2,
              const unsigned short* __restrict__ vTcat,
              float* __restrict__ out, float* __restrict__ P)
{
  const B3 b = xcd_remap(8, 16, 2);
  const int bx = b.bx, by = b.by, z = b.bz;
  const unsigned short* A = ((bx < 4) ? S1 : S2) + (size_t)z * 2048;
  const unsigned short* B = vTcat + (size_t)z * 2048;

  f32x4 acc[8][4];
  core256(A, NTOK, B, NTOK, 2048, by, bx, acc);

  const int t = threadIdx.x, w = t >> 6, l = t & 63;
  const int wr = w >> 2, wc = w & 3;
  const int r4 = (l >> 4) * 4, c = l & 15;
  const int row0 = by * 256 + wr * 128;
  const int col0 = bx * 256 + wc * 64;

#pragma unroll
  for (int mf = 0; mf < 8; ++mf)
#pragma unroll
    for (int nf = 0; nf < 4; ++nf)
#pragma unroll
      for (int i = 0; i < 4; ++i) {
        const int r = row0 + mf*16 + r4 + i;
        const int cg = col0 + nf*16 + c;
        if (z) {
          P[(size_t)r * 2048 + cg] = acc[mf][nf][i];
        } else {
          float* dst = (cg < 1024) ? (out + (size_t)r * 1024 + cg)
                                   : (out + 4194304 + (size_t)r * 1024 + (cg - 1024));
          *dst = acc[mf][nf][i];
        }
      }
}

// out(+4M) += P, remapping [4096 x 2048] partial onto the two context halves
__global__ __launch_bounds__(256)
void add_pv(float* __restrict__ out, const float* __restrict__ P)
{
  const int idx = blockIdx.x * 256 + threadIdx.x;   // 2M threads, 4 floats each
  const int r  = idx >> 9;
  const int c4 = (idx & 511) << 2;
  const float4v p = *(const float4v*)(P + (size_t)r * 2048 + c4);
  float* dst = (c4 < 1024) ? (out + (size_t)r * 1024 + c4)
                           : (out + 4194304 + (size_t)r * 1024 + (c4 - 1024));
  float4v a = *(const float4v*)dst;
#pragma unroll
  for (int j = 0; j < 4; ++j) a[j] += p[j];
  *(float4v*)dst = a;
}

// ---------- row softmax, in place on bf16 [4096 x 4096] ----------
__global__ __launch_bounds__(256)
void softmax_inplace(unsigned short* __restrict__ S)
{
  const int row = blockIdx.x;
  unsigned short* r = S + (size_t)row * NTOK;
  const int t = threadIdx.x, wave = t >> 6, lane = t & 63;
  __shared__ float red[4];

  bf16x8 d0 = *(const bf16x8*)(r + t * 8);
  bf16x8 d1 = *(const bf16x8*)(r + 2048 + t * 8);
  float v[16];
  {
    const unsigned short* p0 = (const unsigned short*)&d0;
    const unsigned short* p1 = (const unsigned short*)&d1;
#pragma unroll
    for (int j = 0; j < 8; ++j) { v[j] = bf2f(p0[j]); v[8 + j] = bf2f(p1[j]); }
  }
  float mx = v[0];
#pragma unroll
  for (int j = 1; j < 16; ++j) mx = fmaxf(mx, v[j]);
#pragma unroll
  for (int o = 32; o > 0; o >>= 1) mx = fmaxf(mx, __shfl_xor(mx, o));
  if (lane == 0) red[wave] = mx;
  __syncthreads();
  mx = fmaxf(fmaxf(red[0], red[1]), fmaxf(red[2], red[3]));

  float s = 0.f;
#pragma unroll
  for (int j = 0; j < 16; ++j) { v[j] = __expf(v[j] - mx); s += v[j]; }
#pragma unroll
  for (int o = 32; o > 0; o >>= 1) s += __shfl_xor(s, o);
  __syncthreads();
  if (lane == 0) red[wave] = s;
  __syncthreads();
  s = red[0] + red[1] + red[2] + red[3];
  const float inv = 1.0f / s;

  unsigned short o0[8], o1[8];
#pragma unroll
  for (int j = 0; j < 8; ++j) { o0[j] = f2bf(v[j] * inv); o1[j] = f2bf(v[8 + j] * inv); }
  *(bf16x8*)(r + t * 8)        = *(const bf16x8*)o0;
  *(bf16x8*)(r + 2048 + t * 8) = *(const bf16x8*)o1;
}

// ---------- fp32 -> bf16 converters ----------
__global__ __launch_bounds__(256)
void cvt2(const float* __restrict__ a, const float* __restrict__ b,
          unsigned short* __restrict__ oa, unsigned short* __restrict__ ob)
{
  const float* in = blockIdx.y ? b : a;
  unsigned short* out = blockIdx.y ? ob : oa;
  const size_t i = ((size_t)blockIdx.x * 256 + threadIdx.x) * 4;
  float4v x = *(const float4v*)(in + i);
  short4v o;
#pragma unroll
  for (int j = 0; j < 4; ++j) o[j] = (short)f2bf(x[j]);
  *(short4v*)(out + i) = o;
}

__global__ __launch_bounds__(256)
void cvt_w(const float* w0, const float* w1, const float* w2,
           const float* w3, const float* w4, const float* w5,
           unsigned short* __restrict__ W6)
{
  const float* srcs[6] = {w0, w1, w2, w3, w4, w5};
  const float* in = srcs[blockIdx.y];
  unsigned short* out = W6 + (size_t)blockIdx.y * (DIM * DIM);
  const size_t i = ((size_t)blockIdx.x * 256 + threadIdx.x) * 4;
  float4v x = *(const float4v*)(in + i);
  short4v o;
#pragma unroll
  for (int j = 0; j < 4; ++j) o[j] = (short)f2bf(x[j]);
  *(short4v*)(out + i) = o;
}

// ---------- host launcher ----------
extern "C" void kernel_launch(void* const* d_in, const int* in_sizes, int n_in,
                              void* d_out, int out_size, void* d_ws, size_t ws_size,
                              hipStream_t stream)
{
  const float* x1  = (const float*)d_in[0];
  const float* x2  = (const float*)d_in[1];
  const float* Wq1 = (const float*)d_in[2];  const float* bq1 = (const float*)d_in[3];
  const float* Wk1 = (const float*)d_in[4];  const float* bk1 = (const float*)d_in[5];
  const float* Wv1 = (const float*)d_in[6];  const float* bv1 = (const float*)d_in[7];
  const float* Wq2 = (const float*)d_in[8];  const float* bq2 = (const float*)d_in[9];
  const float* Wk2 = (const float*)d_in[10]; const float* bk2 = (const float*)d_in[11];
  const float* Wv2 = (const float*)d_in[12]; const float* bv2 = (const float*)d_in[13];
  float* out = (float*)d_out;

  // ws layout (ushort units):
  //  [0,16M):    x1b(4M) x2b(4M) W6(6M) pad -> later S1 [4096x4096]
  //  [16M,32M):  S2
  //  [32M,48M):  q1 k1 q2 k2 (4M each)      -> later P (fp32 partial, 32 MB)
  //  [48M,56M):  v1T v2T (vTcat, [2048 x 4096])
  unsigned short* ws  = (unsigned short*)d_ws;
  const size_t NTD = (size_t)NTOK * DIM;           // 4M elems
  const size_t SM  = (size_t)NTOK * NTOK;          // 16M elems
  unsigned short* x1b = ws;
  unsigned short* x2b = x1b + NTD;
  unsigned short* W6  = x2b + NTD;
  unsigned short* S1  = ws;
  unsigned short* S2  = ws + SM;
  unsigned short* q1  = ws + 2 * SM;
  unsigned short* k1  = q1 + NTD;
  unsigned short* q2  = k1 + NTD;
  unsigned short* k2  = q2 + NTD;
  unsigned short* vT  = k2 + NTD;                  // v1T followed by v2T
  unsigned short* v1T = vT;
  unsigned short* v2T = vT + NTD;
  float* P = (float*)q1;                           // 32 MB partial over dead q/k

  const dim3 blk(256);
  cvt2 <<<dim3(NTD / 1024, 2), blk, 0, stream>>>(x1, x2, x1b, x2b);
  cvt_w<<<dim3((DIM * DIM) / 1024, 6), blk, 0, stream>>>(Wq1, Wk1, Wv1, Wq2, Wk2, Wv2, W6);

  qkv256<<<dim3(DIM / 256, NTOK / 256, 6), dim3(512), 0, stream>>>(
      x1b, x2b, W6, bq1, bk1, bv1, bq2, bk2, bv2, q1, k1, v1T, q2, k2, v2T);

  const float scale = 0.03125f;  // 1/sqrt(1024)

  // scores + softmax (S1 overwrites dead x/W region)
  gemm256_scores<<<dim3(NTOK / 256, NTOK / 256), dim3(512), 0, stream>>>(q2, k1, S1, scale);
  softmax_inplace<<<dim3(NTOK), blk, 0, stream>>>(S1);
  gemm256_scores<<<dim3(NTOK / 256, NTOK / 256), dim3(512), 0, stream>>>(q1, k2, S2, scale);
  softmax_inplace<<<dim3(NTOK), blk, 0, stream>>>(S2);

  // fused PV over [v1T; v2T], split-K=2 (q/k region now dead -> P)
  pv_fused<<<dim3(8, NTOK / 256, 2), dim3(512), 0, stream>>>(S1, S2, vT, out, P);
  add_pv<<<dim3(8192), blk, 0, stream>>>(out, P);
}